// Round 2
// baseline (804.172 us; speedup 1.0000x reference)
//
#include <hip/hip_runtime.h>
#include <math.h>

#define BB 32
#define CC 256
#define HW 16384          // 128*128
#define HW4 4096          // HW/4 (float4 units)
#define BC (BB*CC)        // 8192
#define QB 8              // images per quarter (8 * 16 MiB = 128 MiB < 256 MiB L3)
#define NQ 4

// ws layout (floats):
// [0, 8192)                    pooled[b*256+c]
// [8192, 8192+2097152)         xnp[cg][b][hw]  (4 cgroups x 32 b x 16384 hw)
// [2105344, 2105344+16384)     entro[hw]
// [2121728]                    sig_sum accumulator
#define XN_OFF    8192
#define ENTRO_OFF (XN_OFF + 4*BB*HW)      // 2105344
#define SIG_OFF   (ENTRO_OFF + HW)        // 2121728

// One quarter of (b,c) rows: 2048 blocks, each averages one 64 KiB image-channel.
__global__ __launch_bounds__(256) void pool_kernel(const float* __restrict__ x,
                                                   float* __restrict__ ws,
                                                   int bc_base) {
    const int bc = bc_base + blockIdx.x;
    const int t  = threadIdx.x;
    const float4* xv = (const float4*)x + (size_t)bc * HW4;
    float s = 0.f;
#pragma unroll
    for (int i = 0; i < 16; ++i) {
        float4 v = xv[t + i * 256];
        s += v.x + v.y + v.z + v.w;
    }
    for (int o = 32; o > 0; o >>= 1) s += __shfl_down(s, o);
    __shared__ float part[4];
    if ((t & 63) == 0) part[t >> 6] = s;
    __syncthreads();
    if (t == 0) {
        float tot = part[0] + part[1] + part[2] + part[3];
        ws[bc] = tot * (1.0f / HW);
    }
    if (bc == 0 && t == 0) ws[SIG_OFF] = 0.f;   // first quarter zeroes sig acc
}

// One quarter of images: 512 blocks = QB(8) x chunk(16) x cgroup(4).
// Re-reads the 128 MiB the matching pool_kernel just streamed -> L3-hot.
// Writes non-atomic partials xnp[cg][b][hw].
__global__ __launch_bounds__(256) void xn_partial_kernel(const float* __restrict__ x,
                                                         float* __restrict__ ws,
                                                         int b_base) {
    const int bid   = blockIdx.x;
    const int cg    = bid & 3;
    const int chunk = (bid >> 2) & 15;
    const int b     = b_base + (bid >> 6);
    const int t     = threadIdx.x;

    __shared__ float spool[64];
    if (t < 64) spool[t] = ws[b * CC + cg * 64 + t];
    __syncthreads();

    const float4* xv = (const float4*)x;
    const size_t base = (size_t)b * CC * HW4 + (size_t)(cg * 64) * HW4
                      + (size_t)chunk * 256 + t;

    float ax = 0.f, ay = 0.f, az = 0.f, aw = 0.f;
#pragma unroll 8
    for (int c = 0; c < 64; ++c) {
        float4 v = xv[base + (size_t)c * HW4];
        float p = spool[c];
        ax += v.x * p; ay += v.y * p; az += v.z * p; aw += v.w * p;
    }
    float4 o; o.x = ax; o.y = ay; o.z = az; o.w = aw;
    float4* xnp = (float4*)(ws + XN_OFF);
    xnp[(size_t)(cg * BB + b) * HW4 + chunk * 256 + t] = o;
}

// 16 blocks x 256 threads: one float4 of hw per thread.
// Sums the 4 channel-group partials -> xn[b][hw], accumulates
// entro[hw] (deterministic, no atomics) and the sigmoid sum.
__global__ __launch_bounds__(256) void entro_sig_kernel(float* __restrict__ ws) {
    const int j = blockIdx.x * 256 + threadIdx.x;   // float4 index in [0,4096)
    const int t = threadIdx.x;
    const float4* xnp = (const float4*)(ws + XN_OFF);
    const float inv_c = 1.0f / CC;

    float ex = 0.f, ey = 0.f, ez = 0.f, ew = 0.f;
    float sg = 0.f;
#pragma unroll 4
    for (int b = 0; b < BB; ++b) {
        float4 s0 = xnp[(size_t)(0 * BB + b) * HW4 + j];
        float4 s1 = xnp[(size_t)(1 * BB + b) * HW4 + j];
        float4 s2 = xnp[(size_t)(2 * BB + b) * HW4 + j];
        float4 s3 = xnp[(size_t)(3 * BB + b) * HW4 + j];
        float xnx = (s0.x + s1.x + s2.x + s3.x) * inv_c;
        float xny = (s0.y + s1.y + s2.y + s3.y) * inv_c;
        float xnz = (s0.z + s1.z + s2.z + s3.z) * inv_c;
        float xnw = (s0.w + s1.w + s2.w + s3.w) * inv_c;
        ex += xnx; ey += xny; ez += xnz; ew += xnw;
        sg += 1.f / (1.f + expf(-xnx)) + 1.f / (1.f + expf(-xny)) +
              1.f / (1.f + expf(-xnz)) + 1.f / (1.f + expf(-xnw));
    }
    const float inv_b = 1.0f / BB;
    float4 e; e.x = ex * inv_b; e.y = ey * inv_b; e.z = ez * inv_b; e.w = ew * inv_b;
    ((float4*)(ws + ENTRO_OFF))[j] = e;

    for (int o = 32; o > 0; o >>= 1) sg += __shfl_down(sg, o);
    __shared__ float part[4];
    if ((t & 63) == 0) part[t >> 6] = sg;
    __syncthreads();
    if (t == 0) {
        float tot = part[0] + part[1] + part[2] + part[3];
        atomicAdd(&ws[SIG_OFF], tot);
    }
}

__global__ __launch_bounds__(256) void finalize_kernel(const float* __restrict__ ws,
                                                       float* __restrict__ out) {
    const int t = threadIdx.x;
    const float4* ev = (const float4*)(ws + ENTRO_OFF);

    float lmin = INFINITY, lmax = -INFINITY;
#pragma unroll
    for (int i = 0; i < 16; ++i) {
        float4 v = ev[t + i * 256];
        lmin = fminf(lmin, fminf(fminf(v.x, v.y), fminf(v.z, v.w)));
        lmax = fmaxf(lmax, fmaxf(fmaxf(v.x, v.y), fmaxf(v.z, v.w)));
    }
    for (int o = 32; o > 0; o >>= 1) {
        lmin = fminf(lmin, __shfl_down(lmin, o));
        lmax = fmaxf(lmax, __shfl_down(lmax, o));
    }
    __shared__ float smin[4], smax[4];
    __shared__ float bmin, bmax;
    if ((t & 63) == 0) { smin[t >> 6] = lmin; smax[t >> 6] = lmax; }
    __syncthreads();
    if (t == 0) {
        bmin = fminf(fminf(smin[0], smin[1]), fminf(smin[2], smin[3]));
        bmax = fmaxf(fmaxf(smax[0], smax[1]), fmaxf(smax[2], smax[3]));
    }
    __shared__ unsigned int hist[256];
    hist[t] = 0u;
    __syncthreads();

    const float emin = bmin, emax = bmax;
    const float scale = 256.0f / (emax - emin);
#pragma unroll
    for (int i = 0; i < 16; ++i) {
        float4 v = ev[t + i * 256];
        int i0 = (int)floorf((v.x - emin) * scale);
        int i1 = (int)floorf((v.y - emin) * scale);
        int i2 = (int)floorf((v.z - emin) * scale);
        int i3 = (int)floorf((v.w - emin) * scale);
        i0 = i0 < 0 ? 0 : (i0 > 255 ? 255 : i0);
        i1 = i1 < 0 ? 0 : (i1 > 255 ? 255 : i1);
        i2 = i2 < 0 ? 0 : (i2 > 255 ? 255 : i2);
        i3 = i3 < 0 ? 0 : (i3 > 255 ? 255 : i3);
        atomicAdd(&hist[i0], 1u);
        atomicAdd(&hist[i1], 1u);
        atomicAdd(&hist[i2], 1u);
        atomicAdd(&hist[i3], 1u);
    }
    __syncthreads();

    const unsigned int h = hist[t];
    const float his = (float)h * (1.0f / HW);
    float term = (h > 0u) ? his * (-logf(his + 1e-8f)) : 0.f;
    float nzf  = (h > 0u) ? 1.f : 0.f;
    for (int o = 32; o > 0; o >>= 1) {
        term += __shfl_down(term, o);
        nzf  += __shfl_down(nzf, o);
    }
    __shared__ float sterm[4], snz[4];
    if ((t & 63) == 0) { sterm[t >> 6] = term; snz[t >> 6] = nzf; }
    __syncthreads();
    if (t == 0) {
        float ent = sterm[0] + sterm[1] + sterm[2] + sterm[3];
        float nz  = snz[0] + snz[1] + snz[2] + snz[3];
        float sig = ws[SIG_OFF] * (1.0f / ((float)BB * (float)HW));
        out[0] = sig + (ent / nz) * 10.0f;
    }
}

extern "C" void kernel_launch(void* const* d_in, const int* in_sizes, int n_in,
                              void* d_out, int out_size, void* d_ws, size_t ws_size,
                              hipStream_t stream) {
    const float* x = (const float*)d_in[0];
    float* out = (float*)d_out;
    float* ws  = (float*)d_ws;

    // L3-blocked schedule: pool(q) streams 128 MiB of x through the 256 MiB
    // Infinity Cache; xn(q) immediately re-reads the same 128 MiB -> L3-hot.
    for (int q = 0; q < NQ; ++q) {
        pool_kernel<<<QB * CC, 256, 0, stream>>>(x, ws, q * QB * CC);
        xn_partial_kernel<<<QB * 16 * 4, 256, 0, stream>>>(x, ws, q * QB);
    }
    entro_sig_kernel<<<16, 256, 0, stream>>>(ws);
    finalize_kernel<<<1, 256, 0, stream>>>(ws, out);
}

// Round 3
// 701.435 us; speedup vs baseline: 1.1465x; 1.1465x over previous
//
#include <hip/hip_runtime.h>
#include <math.h>

#define BB 32
#define CC 256
#define HW 16384          // 128*128
#define HW4 4096          // HW/4 (float4 units)
#define CG 16             // channel groups per image
#define CPG 16            // channels per group (256/16)

// ws layout (floats):
// [0, 8388608)                xnp[cg][b][hw]  (16 cg x 32 b x 16384 hw) = 32 MiB
// [8388608, 8404992)          entro[hw]
// [8404992]                   sig_sum accumulator
#define XNP_OFF   0
#define ENTRO_OFF (CG*BB*HW)              // 8388608
#define SIG_OFF   (ENTRO_OFF + HW)        // 8404992

// Single pass over x. Block = (b, cg): 1024 threads, 16 channels.
// Per channel: each thread holds 16 elements (4 float4) in registers,
// block-reduces the channel mean, then acc += mean * v. pooled[b,c] is
// never materialized -- it depends only on channel (b,c), so the fusion
// is exact. Halves x traffic vs the two-pass versions (512 MiB vs 1 GiB).
__global__ __launch_bounds__(1024) void fused_kernel(const float* __restrict__ x,
                                                     float* __restrict__ ws) {
    const int bid = blockIdx.x;
    const int b   = bid >> 4;
    const int cg  = bid & 15;
    const int t   = threadIdx.x;      // 0..1023
    const int wid = t >> 6;           // wave 0..15
    const int lane = t & 63;

    if (bid == 0 && t == 0) ws[SIG_OFF] = 0.f;   // consumed only by combine (after us)

    const float4* xv = (const float4*)x + ((size_t)b * CC + (size_t)cg * CPG) * HW4;

    __shared__ float wsum[16];
    __shared__ float smean;

    float4 a0 = {0,0,0,0}, a1 = {0,0,0,0}, a2 = {0,0,0,0}, a3 = {0,0,0,0};

    for (int c = 0; c < CPG; ++c) {
        const float4* p = xv + (size_t)c * HW4;
        float4 v0 = p[t];
        float4 v1 = p[t + 1024];
        float4 v2 = p[t + 2048];
        float4 v3 = p[t + 3072];

        float s = v0.x + v0.y + v0.z + v0.w
                + v1.x + v1.y + v1.z + v1.w
                + v2.x + v2.y + v2.z + v2.w
                + v3.x + v3.y + v3.z + v3.w;
        for (int o = 32; o > 0; o >>= 1) s += __shfl_down(s, o);
        if (lane == 0) wsum[wid] = s;
        __syncthreads();
        if (t < 16) {
            float ss = wsum[t];
            for (int o = 8; o > 0; o >>= 1) ss += __shfl_down(ss, o);
            if (t == 0) smean = ss * (1.0f / HW);
        }
        __syncthreads();
        const float m = smean;
        a0.x += m * v0.x; a0.y += m * v0.y; a0.z += m * v0.z; a0.w += m * v0.w;
        a1.x += m * v1.x; a1.y += m * v1.y; a1.z += m * v1.z; a1.w += m * v1.w;
        a2.x += m * v2.x; a2.y += m * v2.y; a2.z += m * v2.z; a2.w += m * v2.w;
        a3.x += m * v3.x; a3.y += m * v3.y; a3.z += m * v3.z; a3.w += m * v3.w;
    }

    float4* xnp = (float4*)(ws + XNP_OFF) + ((size_t)cg * BB + b) * HW4;
    xnp[t]        = a0;
    xnp[t + 1024] = a1;
    xnp[t + 2048] = a2;
    xnp[t + 3072] = a3;
}

// 16 blocks x 1024 threads. Thread (bq, jl): j = bid*256 + jl covers one
// float4 of hw; bq = t>>8 covers 8 images. Sums the 16 cg-partials
// (deterministic, no atomics on entro), computes sigmoid partials, and
// LDS-combines the 4 b-quarters for entro.
__global__ __launch_bounds__(1024) void combine_kernel(float* __restrict__ ws) {
    const int t  = threadIdx.x;
    const int jl = t & 255;
    const int j  = blockIdx.x * 256 + jl;   // float4 index 0..4095
    const int bq = t >> 8;                  // 0..3
    const float4* xnp = (const float4*)(ws + XNP_OFF);
    const float inv_c = 1.0f / CC;

    float ex = 0.f, ey = 0.f, ez = 0.f, ew = 0.f, sg = 0.f;
    for (int bb = 0; bb < 8; ++bb) {
        const int b = bq * 8 + bb;
        float ax = 0.f, ay = 0.f, az = 0.f, aw = 0.f;
#pragma unroll
        for (int cg = 0; cg < CG; ++cg) {
            float4 s = xnp[((size_t)cg * BB + b) * HW4 + j];
            ax += s.x; ay += s.y; az += s.z; aw += s.w;
        }
        float xnx = ax * inv_c, xny = ay * inv_c, xnz = az * inv_c, xnw = aw * inv_c;
        ex += xnx; ey += xny; ez += xnz; ew += xnw;
        sg += 1.f / (1.f + expf(-xnx)) + 1.f / (1.f + expf(-xny)) +
              1.f / (1.f + expf(-xnz)) + 1.f / (1.f + expf(-xnw));
    }

    __shared__ float4 epart[4][256];
    float4 ep; ep.x = ex; ep.y = ey; ep.z = ez; ep.w = ew;
    epart[bq][jl] = ep;
    __syncthreads();
    if (bq == 0) {
        float4 e0 = epart[0][jl], e1 = epart[1][jl], e2 = epart[2][jl], e3 = epart[3][jl];
        const float inv_b = 1.0f / BB;
        float4 e;
        e.x = (e0.x + e1.x + e2.x + e3.x) * inv_b;
        e.y = (e0.y + e1.y + e2.y + e3.y) * inv_b;
        e.z = (e0.z + e1.z + e2.z + e3.z) * inv_b;
        e.w = (e0.w + e1.w + e2.w + e3.w) * inv_b;
        ((float4*)(ws + ENTRO_OFF))[j] = e;
    }

    for (int o = 32; o > 0; o >>= 1) sg += __shfl_down(sg, o);
    __shared__ float part[16];
    if ((t & 63) == 0) part[t >> 6] = sg;
    __syncthreads();
    if (t == 0) {
        float tot = 0.f;
#pragma unroll
        for (int i = 0; i < 16; ++i) tot += part[i];
        atomicAdd(&ws[SIG_OFF], tot);
    }
}

__global__ __launch_bounds__(256) void finalize_kernel(const float* __restrict__ ws,
                                                       float* __restrict__ out) {
    const int t = threadIdx.x;
    const float4* ev = (const float4*)(ws + ENTRO_OFF);

    float lmin = INFINITY, lmax = -INFINITY;
#pragma unroll
    for (int i = 0; i < 16; ++i) {
        float4 v = ev[t + i * 256];
        lmin = fminf(lmin, fminf(fminf(v.x, v.y), fminf(v.z, v.w)));
        lmax = fmaxf(lmax, fmaxf(fmaxf(v.x, v.y), fmaxf(v.z, v.w)));
    }
    for (int o = 32; o > 0; o >>= 1) {
        lmin = fminf(lmin, __shfl_down(lmin, o));
        lmax = fmaxf(lmax, __shfl_down(lmax, o));
    }
    __shared__ float smin[4], smax[4];
    __shared__ float bmin, bmax;
    if ((t & 63) == 0) { smin[t >> 6] = lmin; smax[t >> 6] = lmax; }
    __syncthreads();
    if (t == 0) {
        bmin = fminf(fminf(smin[0], smin[1]), fminf(smin[2], smin[3]));
        bmax = fmaxf(fmaxf(smax[0], smax[1]), fmaxf(smax[2], smax[3]));
    }
    __shared__ unsigned int hist[256];
    hist[t] = 0u;
    __syncthreads();

    const float emin = bmin, emax = bmax;
    const float scale = 256.0f / (emax - emin);
#pragma unroll
    for (int i = 0; i < 16; ++i) {
        float4 v = ev[t + i * 256];
        int i0 = (int)floorf((v.x - emin) * scale);
        int i1 = (int)floorf((v.y - emin) * scale);
        int i2 = (int)floorf((v.z - emin) * scale);
        int i3 = (int)floorf((v.w - emin) * scale);
        i0 = i0 < 0 ? 0 : (i0 > 255 ? 255 : i0);
        i1 = i1 < 0 ? 0 : (i1 > 255 ? 255 : i1);
        i2 = i2 < 0 ? 0 : (i2 > 255 ? 255 : i2);
        i3 = i3 < 0 ? 0 : (i3 > 255 ? 255 : i3);
        atomicAdd(&hist[i0], 1u);
        atomicAdd(&hist[i1], 1u);
        atomicAdd(&hist[i2], 1u);
        atomicAdd(&hist[i3], 1u);
    }
    __syncthreads();

    const unsigned int h = hist[t];
    const float his = (float)h * (1.0f / HW);
    float term = (h > 0u) ? his * (-logf(his + 1e-8f)) : 0.f;
    float nzf  = (h > 0u) ? 1.f : 0.f;
    for (int o = 32; o > 0; o >>= 1) {
        term += __shfl_down(term, o);
        nzf  += __shfl_down(nzf, o);
    }
    __shared__ float sterm[4], snz[4];
    if ((t & 63) == 0) { sterm[t >> 6] = term; snz[t >> 6] = nzf; }
    __syncthreads();
    if (t == 0) {
        float ent = sterm[0] + sterm[1] + sterm[2] + sterm[3];
        float nz  = snz[0] + snz[1] + snz[2] + snz[3];
        float sig = ws[SIG_OFF] * (1.0f / ((float)BB * (float)HW));
        out[0] = sig + (ent / nz) * 10.0f;
    }
}

extern "C" void kernel_launch(void* const* d_in, const int* in_sizes, int n_in,
                              void* d_out, int out_size, void* d_ws, size_t ws_size,
                              hipStream_t stream) {
    const float* x = (const float*)d_in[0];
    float* out = (float*)d_out;
    float* ws  = (float*)d_ws;

    fused_kernel<<<BB * CG, 1024, 0, stream>>>(x, ws);
    combine_kernel<<<16, 1024, 0, stream>>>(ws);
    finalize_kernel<<<1, 256, 0, stream>>>(ws, out);
}